// Round 9
// baseline (104.365 us; speedup 1.0000x reference)
//
#include <hip/hip_runtime.h>
#include <hip/hip_bf16.h>

typedef __attribute__((ext_vector_type(8))) short bf16x8;
typedef __attribute__((ext_vector_type(4))) float f32x4;

#define D_DIM 256     // input feature dim
#define H_DIM 128     // hidden dim per branch
#define MAX_RS 25088  // rows per LDS half-range (100352 B f32 accumulator)
#define NSLICE 128    // edge slices = blocks (1 per CU, 100KB LDS each)

// RNE float->bf16 (bit pattern)
__device__ inline ushort f2bf(float f) {
    union { float f; unsigned u; } a; a.f = f;
    unsigned r = a.u + 0x7fffu + ((a.u >> 16) & 1u);
    return (ushort)(r >> 16);
}
__device__ inline float bf2f(unsigned hi16) {
    union { unsigned u; float f; } a; a.u = hi16 << 16;
    return a.f;
}

// K0: build Wt bf16 [hcat][k]; init dis only for fallback path.
__global__ void k0_init(const float* __restrict__ W_nb, const float* __restrict__ W_self,
                        ushort* __restrict__ Wt, float* __restrict__ dis, int N, int init_dis) {
    int i = blockIdx.x * 256 + threadIdx.x;
    if (i < 2 * H_DIM * D_DIM) {
        int sel = i >> 15;
        int r   = i & 32767;
        int k   = r >> 7;
        int h   = r & 127;
        const float* W = sel ? W_self : W_nb;
        Wt[(sel * H_DIM + h) * D_DIM + k] = f2bf(W[k * H_DIM + h]);
    }
    if (init_dis && i < N) dis[i] = 1e-10f;
}

// K1: persistent-B fused GEMM (unchanged from R6).
__global__ __launch_bounds__(512, 2) void k1_gemm(
    const float* __restrict__ x, const ushort* __restrict__ Wt,
    const float* __restrict__ b_nb, const float* __restrict__ b_self,
    const float* __restrict__ W_att,
    float* __restrict__ g_nb, float* __restrict__ g_self, int N, int ntiles)
{
    __shared__ __align__(16) ushort A_lds[64][264];
    __shared__ float part[2][2][64];

    const int t    = threadIdx.x;
    const int lane = t & 63;
    const int w    = t >> 6;
    const int rh   = w >> 2;
    const int cg   = w & 3;
    const int br   = cg >> 1;
    const int ch   = cg & 1;
    const int li   = lane & 15;
    const int grp  = lane >> 4;

    float bias[4], aw[4];
    #pragma unroll
    for (int ni = 0; ni < 4; ni++) {
        int hh = ch * 64 + ni * 16 + li;
        bias[ni] = br ? b_self[hh] : b_nb[hh];
        aw[ni]   = W_att[br * H_DIM + hh];
    }

    bf16x8 Bf[4][8];
    #pragma unroll
    for (int ni = 0; ni < 4; ni++)
        #pragma unroll
        for (int ks = 0; ks < 8; ks++)
            Bf[ni][ks] = *reinterpret_cast<const bf16x8*>(
                Wt + (size_t)(cg * 64 + ni * 16 + li) * D_DIM + ks * 32 + grp * 8);

    const int sr = t >> 3;
    const int sc = t & 7;

    for (int rt = blockIdx.x; rt < ntiles; rt += gridDim.x) {
        const int row0 = rt * 64;

        __syncthreads();
        {
            const int gr = row0 + sr;
            const bool v = gr < N;
            const float4* src = reinterpret_cast<const float4*>(x + (size_t)gr * D_DIM);
            #pragma unroll
            for (int j = 0; j < 8; j++) {
                int c4 = sc + j * 8;
                ushort4 o;
                if (v) {
                    float4 f = src[c4];
                    o.x = f2bf(f.x); o.y = f2bf(f.y); o.z = f2bf(f.z); o.w = f2bf(f.w);
                } else { o.x = 0; o.y = 0; o.z = 0; o.w = 0; }
                *reinterpret_cast<ushort4*>(&A_lds[sr][c4 * 4]) = o;
            }
        }
        __syncthreads();

        f32x4 acc[2][4];
        #pragma unroll
        for (int mi = 0; mi < 2; mi++)
            #pragma unroll
            for (int ni = 0; ni < 4; ni++) acc[mi][ni] = f32x4{0.f, 0.f, 0.f, 0.f};

        #pragma unroll
        for (int ks = 0; ks < 8; ks++) {
            bf16x8 af0 = *reinterpret_cast<const bf16x8*>(&A_lds[rh * 32 + li][ks * 32 + grp * 8]);
            bf16x8 af1 = *reinterpret_cast<const bf16x8*>(&A_lds[rh * 32 + 16 + li][ks * 32 + grp * 8]);
            #pragma unroll
            for (int ni = 0; ni < 4; ni++) {
                acc[0][ni] = __builtin_amdgcn_mfma_f32_16x16x32_bf16(af0, Bf[ni][ks], acc[0][ni], 0, 0, 0);
                acc[1][ni] = __builtin_amdgcn_mfma_f32_16x16x32_bf16(af1, Bf[ni][ks], acc[1][ni], 0, 0, 0);
            }
        }

        float p[2][4];
        #pragma unroll
        for (int mi = 0; mi < 2; mi++)
            #pragma unroll
            for (int r4 = 0; r4 < 4; r4++) p[mi][r4] = 0.f;
        #pragma unroll
        for (int ni = 0; ni < 4; ni++)
            #pragma unroll
            for (int mi = 0; mi < 2; mi++)
                #pragma unroll
                for (int r4 = 0; r4 < 4; r4++) {
                    float y = acc[mi][ni][r4] + bias[ni];
                    y = y > 0.f ? y : 0.f;
                    p[mi][r4] += y * aw[ni];
                }
        #pragma unroll
        for (int mi = 0; mi < 2; mi++)
            #pragma unroll
            for (int r4 = 0; r4 < 4; r4++) {
                float v = p[mi][r4];
                #pragma unroll
                for (int m = 1; m < 16; m <<= 1) v += __shfl_xor(v, m);
                if (li == 0)
                    part[br][ch][rh * 32 + mi * 16 + grp * 4 + r4] = v;
            }
        __syncthreads();

        if (t < 128) {
            int b_ = t >> 6, lr = t & 63;
            int gr = row0 + lr;
            if (gr < N) {
                float val = part[b_][0][lr] + part[b_][1][lr];
                if (b_) g_self[gr] = val; else g_nb[gr] = val;
            }
        }
    }
}

// K2S: single-pass fused gate + LDS rowsum. 128 blocks x 1024 thr, 100KB LDS.
// Phase 1: stream slice once; m -> out[e]; row<RS -> LDS atomic; row>=RS -> spill
//          (row,m) to per-block region (stays in own XCD L2).
// Flush half-A bf16 partials; zero acc; phase 2: replay own spills; flush half-B.
__global__ __launch_bounds__(1024, 1) void k2s_gate_scatter(
    const int* __restrict__ row, const int* __restrict__ col,
    const float* __restrict__ values, const float* __restrict__ noise,
    const float* __restrict__ g_nb, const float* __restrict__ g_self,
    const float* __restrict__ b_att,
    float* __restrict__ out, ushort* __restrict__ priv, uint2* __restrict__ spill,
    int E, int ES, int RS, int Npad)
{
    __shared__ float acc[MAX_RS];
    __shared__ unsigned cur;
    const int s = blockIdx.x;
    const int t = threadIdx.x;

    for (int i = t; i < RS; i += 1024) acc[i] = 0.f;
    if (t == 0) cur = 0;
    __syncthreads();

    const float ba = b_att[0];
    const int base = s * ES;
    int end = base + ES; if (end > E) end = E;
    uint2* sp = spill + (size_t)s * ES;

    // ---- phase 1: stream edges once ----
    for (int e = base + t; e < end; e += 1024) {
        int   r = row[e], c = col[e];
        float v = values[e];
        float u = noise[e] + 1e-7f;
        float la = g_nb[r] + g_self[c] + ba;
        float gate = u / (u + (1.f - u) * __expf(-la));
        float mask = fminf(fmaxf(gate * 1.6f - 0.5f, 0.f), 1.f);
        float m = v * mask;
        out[e] = m;
        if (m != 0.f) {
            if (r < RS) {
                atomicAdd(&acc[r], m);
            } else {
                unsigned p = atomicAdd(&cur, 1u);
                sp[p] = make_uint2((unsigned)(r - RS), __float_as_uint(m));
            }
        }
    }
    __syncthreads();
    const unsigned nsp = cur;

    // ---- flush half-A partials (bf16, packed pairs, coalesced) ----
    ushort* dstA = priv + (size_t)s * Npad;
    for (int i = t * 2; i < RS; i += 2048) {
        unsigned pk = (unsigned)f2bf(acc[i]) | ((unsigned)f2bf(acc[i + 1]) << 16);
        *reinterpret_cast<unsigned*>(dstA + i) = pk;
    }
    __syncthreads();
    for (int i = t; i < RS; i += 1024) acc[i] = 0.f;
    __syncthreads();

    // ---- phase 2: replay own spills (L2-resident) ----
    for (unsigned i = t; i < nsp; i += 1024) {
        uint2 rec = sp[i];
        atomicAdd(&acc[rec.x], __uint_as_float(rec.y));
    }
    __syncthreads();

    // ---- flush half-B partials ----
    ushort* dstB = priv + (size_t)s * Npad + RS;
    for (int i = t * 2; i < RS; i += 2048) {
        unsigned pk = (unsigned)f2bf(acc[i]) | ((unsigned)f2bf(acc[i + 1]) << 16);
        *reinterpret_cast<unsigned*>(dstB + i) = pk;
    }
}

// K2C: dis[n] = rsqrt(1e-10 + sum_s bf16 priv[s][n]); 2 rows/thread, coalesced.
__global__ __launch_bounds__(256) void k2c_reduce(
    const ushort* __restrict__ priv, float* __restrict__ dis, int N, int Npad, int S)
{
    int n0 = (blockIdx.x * 256 + threadIdx.x) * 2;
    if (n0 >= N) return;
    float s0 = 1e-10f, s1 = 1e-10f;
    for (int s = 0; s < S; s++) {
        unsigned v = *reinterpret_cast<const unsigned*>(priv + (size_t)s * Npad + n0);
        s0 += bf2f(v & 0xffffu);
        s1 += bf2f(v >> 16);
    }
    dis[n0] = rsqrtf(s0);
    if (n0 + 1 < N) dis[n0 + 1] = rsqrtf(s1);
}

// Fallback path (N too large for LDS halves): fused gate + global atomic.
__global__ __launch_bounds__(256) void k2_atomic_fb(
    const int* __restrict__ row, const int* __restrict__ col,
    const float* __restrict__ values, const float* __restrict__ noise,
    const float* __restrict__ g_nb, const float* __restrict__ g_self,
    const float* __restrict__ b_att,
    float* __restrict__ out, float* __restrict__ dis, int E)
{
    int e = blockIdx.x * 256 + threadIdx.x;
    if (e >= E) return;
    int   r = row[e], c = col[e];
    float v = values[e];
    float u = noise[e] + 1e-7f;
    float la = g_nb[r] + g_self[c] + b_att[0];
    float gate = u / (u + (1.f - u) * __expf(-la));
    float mask = fminf(fmaxf(gate * 1.6f - 0.5f, 0.f), 1.f);
    float m = v * mask;
    out[e] = m;
    if (m != 0.f) atomicAdd(&dis[r], m);
}
__global__ __launch_bounds__(256) void k2c_rsqrt_fb(float* __restrict__ dis, int N)
{
    int n = blockIdx.x * 256 + threadIdx.x;
    if (n < N) dis[n] = rsqrtf(dis[n]);
}

// K3: symmetric degree normalization, gathers precomputed dis.
__global__ __launch_bounds__(256) void k3_edge2(
    const int* __restrict__ row, const int* __restrict__ col,
    float* __restrict__ out, const float* __restrict__ dis, int E)
{
    int e = blockIdx.x * 256 + threadIdx.x;
    if (e >= E) return;
    out[e] = out[e] * dis[row[e]] * dis[col[e]];
}

extern "C" void kernel_launch(void* const* d_in, const int* in_sizes, int n_in,
                              void* d_out, int out_size, void* d_ws, size_t ws_size,
                              hipStream_t stream) {
    const float* x      = (const float*)d_in[0];
    const float* W_nb   = (const float*)d_in[1];
    const float* b_nb   = (const float*)d_in[2];
    const float* W_self = (const float*)d_in[3];
    const float* b_self = (const float*)d_in[4];
    const float* W_att  = (const float*)d_in[5];
    const float* b_att  = (const float*)d_in[6];
    const float* values = (const float*)d_in[7];
    const float* noise  = (const float*)d_in[8];
    const int*   row    = (const int*)d_in[9];
    const int*   col    = (const int*)d_in[10];

    const int N = in_sizes[0] / D_DIM;
    const int E = in_sizes[7];
    float* out = (float*)d_out;

    int RS = ((N + 1) / 2 + 1) & ~1;       // even rows per half
    const int Npad = 2 * RS;
    const int ES = (E + NSLICE - 1) / NSLICE;

    char* ws = (char*)d_ws;
    ushort* Wt     = (ushort*)ws;                       // 131072 B
    float*  g_nb   = (float*)(ws + 131072);             // N
    float*  g_self = g_nb + N;                          // N
    float*  dis    = g_self + N;                        // N
    ushort* priv   = (ushort*)(dis + N);                // NSLICE * Npad bf16
    // 8B-align spill
    size_t priv_bytes = ((size_t)NSLICE * Npad * 2 + 7) & ~(size_t)7;
    uint2*  spill  = (uint2*)((char*)priv + priv_bytes);// NSLICE * ES records

    size_t need = 131072 + (size_t)3 * N * 4 + priv_bytes + (size_t)NSLICE * ES * 8;
    bool lds_path = (RS <= MAX_RS) && (need <= ws_size);

    int init_n = 2 * H_DIM * D_DIM;
    if (N > init_n) init_n = N;
    k0_init<<<(init_n + 255) / 256, 256, 0, stream>>>(W_nb, W_self, Wt, dis, N, lds_path ? 0 : 1);

    const int ntiles = (N + 63) / 64;
    k1_gemm<<<256, 512, 0, stream>>>(x, Wt, b_nb, b_self, W_att, g_nb, g_self, N, ntiles);

    if (lds_path) {
        k2s_gate_scatter<<<NSLICE, 1024, 0, stream>>>(row, col, values, noise,
                                                      g_nb, g_self, b_att,
                                                      out, priv, spill, E, ES, RS, Npad);
        k2c_reduce<<<((N + 1) / 2 + 255) / 256, 256, 0, stream>>>(priv, dis, N, Npad, NSLICE);
    } else {
        k2_atomic_fb<<<(E + 255) / 256, 256, 0, stream>>>(row, col, values, noise,
                                                          g_nb, g_self, b_att, out, dis, E);
        k2c_rsqrt_fb<<<(N + 255) / 256, 256, 0, stream>>>(dis, N);
    }

    k3_edge2<<<(E + 255) / 256, 256, 0, stream>>>(row, col, out, dis, E);
}

// Round 10
// 76.072 us; speedup vs baseline: 1.3719x; 1.3719x over previous
//
#include <hip/hip_runtime.h>
#include <hip/hip_bf16.h>

typedef __attribute__((ext_vector_type(8))) short bf16x8;
typedef __attribute__((ext_vector_type(4))) float f32x4;

#define D_DIM 256   // input feature dim
#define H_DIM 128   // hidden dim per branch
#define NXCD 8      // XCDs on MI355X

// RNE float->bf16 (bit pattern)
__device__ inline ushort f2bf(float f) {
    union { float f; unsigned u; } a; a.f = f;
    unsigned r = a.u + 0x7fffu + ((a.u >> 16) & 1u);
    return (ushort)(r >> 16);
}

// K0: build Wt bf16 [hcat][k]; zero the 8 per-XCD accumulator copies.
__global__ void k0_init(const float* __restrict__ W_nb, const float* __restrict__ W_self,
                        ushort* __restrict__ Wt, float* __restrict__ priv, int PN) {
    int i = blockIdx.x * 256 + threadIdx.x;
    if (i < 2 * H_DIM * D_DIM) {
        int sel = i >> 15;
        int r   = i & 32767;
        int k   = r >> 7;
        int h   = r & 127;
        const float* W = sel ? W_self : W_nb;
        Wt[(sel * H_DIM + h) * D_DIM + k] = f2bf(W[k * H_DIM + h]);
    }
    if (i < PN) priv[i] = 0.f;
}

// K1: persistent-B fused GEMM (unchanged from R6).
__global__ __launch_bounds__(512, 2) void k1_gemm(
    const float* __restrict__ x, const ushort* __restrict__ Wt,
    const float* __restrict__ b_nb, const float* __restrict__ b_self,
    const float* __restrict__ W_att,
    float* __restrict__ g_nb, float* __restrict__ g_self, int N, int ntiles)
{
    __shared__ __align__(16) ushort A_lds[64][264];
    __shared__ float part[2][2][64];

    const int t    = threadIdx.x;
    const int lane = t & 63;
    const int w    = t >> 6;
    const int rh   = w >> 2;
    const int cg   = w & 3;
    const int br   = cg >> 1;
    const int ch   = cg & 1;
    const int li   = lane & 15;
    const int grp  = lane >> 4;

    float bias[4], aw[4];
    #pragma unroll
    for (int ni = 0; ni < 4; ni++) {
        int hh = ch * 64 + ni * 16 + li;
        bias[ni] = br ? b_self[hh] : b_nb[hh];
        aw[ni]   = W_att[br * H_DIM + hh];
    }

    bf16x8 Bf[4][8];
    #pragma unroll
    for (int ni = 0; ni < 4; ni++)
        #pragma unroll
        for (int ks = 0; ks < 8; ks++)
            Bf[ni][ks] = *reinterpret_cast<const bf16x8*>(
                Wt + (size_t)(cg * 64 + ni * 16 + li) * D_DIM + ks * 32 + grp * 8);

    const int sr = t >> 3;
    const int sc = t & 7;

    for (int rt = blockIdx.x; rt < ntiles; rt += gridDim.x) {
        const int row0 = rt * 64;

        __syncthreads();
        {
            const int gr = row0 + sr;
            const bool v = gr < N;
            const float4* src = reinterpret_cast<const float4*>(x + (size_t)gr * D_DIM);
            #pragma unroll
            for (int j = 0; j < 8; j++) {
                int c4 = sc + j * 8;
                ushort4 o;
                if (v) {
                    float4 f = src[c4];
                    o.x = f2bf(f.x); o.y = f2bf(f.y); o.z = f2bf(f.z); o.w = f2bf(f.w);
                } else { o.x = 0; o.y = 0; o.z = 0; o.w = 0; }
                *reinterpret_cast<ushort4*>(&A_lds[sr][c4 * 4]) = o;
            }
        }
        __syncthreads();

        f32x4 acc[2][4];
        #pragma unroll
        for (int mi = 0; mi < 2; mi++)
            #pragma unroll
            for (int ni = 0; ni < 4; ni++) acc[mi][ni] = f32x4{0.f, 0.f, 0.f, 0.f};

        #pragma unroll
        for (int ks = 0; ks < 8; ks++) {
            bf16x8 af0 = *reinterpret_cast<const bf16x8*>(&A_lds[rh * 32 + li][ks * 32 + grp * 8]);
            bf16x8 af1 = *reinterpret_cast<const bf16x8*>(&A_lds[rh * 32 + 16 + li][ks * 32 + grp * 8]);
            #pragma unroll
            for (int ni = 0; ni < 4; ni++) {
                acc[0][ni] = __builtin_amdgcn_mfma_f32_16x16x32_bf16(af0, Bf[ni][ks], acc[0][ni], 0, 0, 0);
                acc[1][ni] = __builtin_amdgcn_mfma_f32_16x16x32_bf16(af1, Bf[ni][ks], acc[1][ni], 0, 0, 0);
            }
        }

        float p[2][4];
        #pragma unroll
        for (int mi = 0; mi < 2; mi++)
            #pragma unroll
            for (int r4 = 0; r4 < 4; r4++) p[mi][r4] = 0.f;
        #pragma unroll
        for (int ni = 0; ni < 4; ni++)
            #pragma unroll
            for (int mi = 0; mi < 2; mi++)
                #pragma unroll
                for (int r4 = 0; r4 < 4; r4++) {
                    float y = acc[mi][ni][r4] + bias[ni];
                    y = y > 0.f ? y : 0.f;
                    p[mi][r4] += y * aw[ni];
                }
        #pragma unroll
        for (int mi = 0; mi < 2; mi++)
            #pragma unroll
            for (int r4 = 0; r4 < 4; r4++) {
                float v = p[mi][r4];
                #pragma unroll
                for (int m = 1; m < 16; m <<= 1) v += __shfl_xor(v, m);
                if (li == 0)
                    part[br][ch][rh * 32 + mi * 16 + grp * 4 + r4] = v;
            }
        __syncthreads();

        if (t < 128) {
            int b_ = t >> 6, lr = t & 63;
            int gr = row0 + lr;
            if (gr < N) {
                float val = part[b_][0][lr] + part[b_][1][lr];
                if (b_) g_self[gr] = val; else g_nb[gr] = val;
            }
        }
    }
}

// K2: edge pass — gate/mask -> out; rowsum via WORKGROUP-SCOPE atomic into the
// calling XCD's private copy (selected by HW XCC_ID). Workgroup scope keeps the
// RMW in the local XCD L2 (shared by all CUs on that XCD -> correct), avoiding
// the memory-side device-scope atomic funnel. Copies merged in k2b.
__global__ __launch_bounds__(256) void k2_edge1(
    const int* __restrict__ row, const int* __restrict__ col,
    const float* __restrict__ values, const float* __restrict__ noise,
    const float* __restrict__ g_nb, const float* __restrict__ g_self,
    const float* __restrict__ b_att,
    float* __restrict__ mv_out, float* __restrict__ priv, int N, int E)
{
    unsigned xcd;
    asm volatile("s_getreg_b32 %0, hwreg(HW_REG_XCC_ID)" : "=s"(xcd));
    float* myp = priv + (size_t)(xcd & (NXCD - 1)) * N;

    int e = blockIdx.x * 256 + threadIdx.x;
    if (e >= E) return;
    int   r = row[e], c = col[e];
    float v = values[e];
    float u = noise[e] + 1e-7f;
    float la = g_nb[r] + g_self[c] + b_att[0];
    float gate = u / (u + (1.f - u) * __expf(-la));
    float mask = fminf(fmaxf(gate * 1.6f - 0.5f, 0.f), 1.f);
    float m = v * mask;
    mv_out[e] = m;
    if (m != 0.f)
        __hip_atomic_fetch_add(myp + r, m, __ATOMIC_RELAXED, __HIP_MEMORY_SCOPE_WORKGROUP);
}

// K2b: dis[n] = rsqrt(1e-10 + sum over the 8 XCD copies).
__global__ __launch_bounds__(256) void k2b_reduce(
    const float* __restrict__ priv, float* __restrict__ dis, int N)
{
    int n = blockIdx.x * 256 + threadIdx.x;
    if (n >= N) return;
    float s = 1e-10f;
    #pragma unroll
    for (int p = 0; p < NXCD; p++) s += priv[(size_t)p * N + n];
    dis[n] = rsqrtf(s);
}

// K3: symmetric degree normalization, gathers precomputed dis.
__global__ __launch_bounds__(256) void k3_edge2(
    const int* __restrict__ row, const int* __restrict__ col,
    float* __restrict__ out, const float* __restrict__ dis, int E)
{
    int e = blockIdx.x * 256 + threadIdx.x;
    if (e >= E) return;
    out[e] = out[e] * dis[row[e]] * dis[col[e]];
}

extern "C" void kernel_launch(void* const* d_in, const int* in_sizes, int n_in,
                              void* d_out, int out_size, void* d_ws, size_t ws_size,
                              hipStream_t stream) {
    const float* x      = (const float*)d_in[0];
    const float* W_nb   = (const float*)d_in[1];
    const float* b_nb   = (const float*)d_in[2];
    const float* W_self = (const float*)d_in[3];
    const float* b_self = (const float*)d_in[4];
    const float* W_att  = (const float*)d_in[5];
    const float* b_att  = (const float*)d_in[6];
    const float* values = (const float*)d_in[7];
    const float* noise  = (const float*)d_in[8];
    const int*   row    = (const int*)d_in[9];
    const int*   col    = (const int*)d_in[10];

    const int N = in_sizes[0] / D_DIM;
    const int E = in_sizes[7];
    float* out = (float*)d_out;

    char* ws = (char*)d_ws;
    ushort* Wt     = (ushort*)ws;                       // 131072 B
    float*  g_nb   = (float*)(ws + 131072);             // N
    float*  g_self = g_nb + N;                          // N
    float*  dis    = g_self + N;                        // N
    float*  priv   = dis + N;                           // NXCD * N

    const int PN = NXCD * N;

    int init_n = 2 * H_DIM * D_DIM;
    if (PN > init_n) init_n = PN;
    k0_init<<<(init_n + 255) / 256, 256, 0, stream>>>(W_nb, W_self, Wt, priv, PN);

    const int ntiles = (N + 63) / 64;
    k1_gemm<<<256, 512, 0, stream>>>(x, Wt, b_nb, b_self, W_att, g_nb, g_self, N, ntiles);

    int eb1 = (E + 255) / 256;
    k2_edge1<<<eb1, 256, 0, stream>>>(row, col, values, noise, g_nb, g_self, b_att,
                                      out, priv, N, E);
    k2b_reduce<<<(N + 255) / 256, 256, 0, stream>>>(priv, dis, N);
    k3_edge2<<<eb1, 256, 0, stream>>>(row, col, out, dis, E);
}